// Round 10
// baseline (729.279 us; speedup 1.0000x reference)
//
#include <hip/hip_runtime.h>

// AdjointODE: h += dt * ( tanh(h@W1+b1) @ W2 + b2 ), 50 Euler steps.
// BATCH=32768, DIM=128, HID=256.
// ROUND 19: r11 (278us, 2 waves/SIMD, VGPR=100, no spill) + 128-AGPR W2
// CACHE. Allocator model pinned by r10..r18: MFMA kernels split the
// unified file -- 2 waves/SIMD: 128 arch + 128 AGPR; 1 wave/SIMD: 256+256.
// Exceed the ARCH half -> scratch spill (allocator never borrows AGPRs
// for ds_read/VALU values on its own). r11's arch half has ~28 regs
// headroom and its AGPR half is IDLE -> cache exactly 4 of 8 W2 chunks
// (32 frags x 4 = 128 AGPRs) there, nothing else changes.
//  - chunks 3..6: mm2 via asm MFMA with A operand "a"-constrained
//    (s_nop 1 prefix; r17-validated correctness mechanism), static
//    indices in an unrolled p=4..7 tail;
//  - chunks 0..2 (runtime p=1..3) + chunk 7 (epilogue) stay streamed
//    with BUILTIN MFMAs -> last writer of h4 before any VALU read is
//    builtin (compiler inserts hazard nops): r17's passing sandwich.
// LDS reads/wave/step 144 -> 112 (-22%); step 13.3k -> ~10.4k cyc.
// Predicted: dur 215-245, FETCH ~9.26MB, VGPR<=128, MfmaUtil ~42.
// LAST register-cache experiment: NaN / GB-FETCH / dur>=280 => revert
// to r11 and declare its LDS-issue roofline final.
// Else identical to r11: 256x512, 2 waves/SIMD, wave owns 16 rows,
// depth-1 rotated pipeline (mm1(p); mm2(p-1); act(p)), fragment-linear
// weight LDS, h fp32-resident, pk2 packing, b1 as accumulator init
// (TSCALE-folded), b2 via VALU fma.

typedef __attribute__((ext_vector_type(8))) short short8;
typedef __attribute__((ext_vector_type(4))) float float4v;
typedef __attribute__((ext_vector_type(4))) int int4v;

union FB { int4v i; short8 s; };

// LDS map (bytes)
#define W1F_OFF 0        // 64 frags (nt*4+c) x 1 KB = 64 KB
#define W2F_OFF 65536    // 64 frags (p*8+tb) x 1 KB = 64 KB
#define B1_OFF  131072   // f32[256] (TSCALE-folded b1)
#define DT_OFF  132096   // f32[64]
#define LDS_BYTES 132352

#define TSCALE 2.8853900817779268f  // 2/ln2: tanh(x) = 1 - 2/(exp2(x*TSCALE)+1)

__device__ __forceinline__ unsigned rne2(float x) {
  unsigned u = __float_as_uint(x);
  return u + 0x7fffu + ((u >> 16) & 1u);
}

#if __has_builtin(__builtin_amdgcn_cvt_pk_bf16_f32)
__device__ __forceinline__ int pk2(float lo, float hi) {
  return __builtin_bit_cast(int, __builtin_amdgcn_cvt_pk_bf16_f32(lo, hi));
}
#else
__device__ __forceinline__ int pk2(float lo, float hi) {
  return (int)__builtin_amdgcn_perm(rne2(hi), rne2(lo), 0x07060302u);
}
#endif

// B-frag for one 32-K chunk from two C-layout float4 tiles (even, odd).
__device__ __forceinline__ int4v packfrag(float4v e, float4v o) {
  int4v f;
  f.x = pk2(e.x, e.y);
  f.y = pk2(e.z, e.w);
  f.z = pk2(o.x, o.y);
  f.w = pk2(o.z, o.w);
  return f;
}

#define MFMA16(a, b, c) __builtin_amdgcn_mfma_f32_16x16x32_bf16(a, b, c, 0, 0, 0)

// mm2 MFMA with A operand pinned to AGPR class at every use.
// s_nop 1 prefix = wait states for any preceding VALU write of an
// operand (the hazard the compiler can't see inside the asm). r17-validated.
__device__ __forceinline__ void mfma_a(float4v& acc, const short8& w, const short8& b) {
  asm("s_nop 1\n\tv_mfma_f32_16x16x32_bf16 %0, %1, %2, %0"
      : "+v"(acc) : "a"(w), "v"(b));
}

extern "C" __global__ __launch_bounds__(512, 2)
void ode_kernel(const float* __restrict__ inp, const float* __restrict__ ts,
                const float* __restrict__ W1, const float* __restrict__ b1,
                const float* __restrict__ W2, const float* __restrict__ b2,
                float* __restrict__ out) {
  __shared__ __align__(16) char ldsb[LDS_BYTES];
  float* b1f = (float*)(ldsb + B1_OFF);
  float* dtf = (float*)(ldsb + DT_OFF);

  const int tid = threadIdx.x;
  const int lane = tid & 63, wave = tid >> 6;
  const int ln = lane & 15;  // batch-row within wave's 16
  const int q = lane >> 4;   // quad
  const int row = blockIdx.x * 128 + wave * 16 + ln;

  // ---- stage W1 frags: pair pi = (fid=nt*4+c)*64 + L; wave covers one frag ----
  #pragma unroll 1
  for (int it = 0; it < 8; it++) {
    const int pi = it * 512 + tid;  // [0, 4096)
    const int fid = pi >> 6, L = pi & 63;
    const int nt = fid >> 2, c = fid & 3;
    const int lf = L & 15, qf = L >> 4;
    const int n = nt * 16 + lf;            // hid index (A-frag m-row)
    const int kb = c * 32 + qf * 4;        // logical dim base
    float v0 = W1[(kb + 0) * 256 + n] * TSCALE;
    float v1 = W1[(kb + 1) * 256 + n] * TSCALE;
    float v2 = W1[(kb + 2) * 256 + n] * TSCALE;
    float v3 = W1[(kb + 3) * 256 + n] * TSCALE;
    float v4 = W1[(kb + 16) * 256 + n] * TSCALE;
    float v5 = W1[(kb + 17) * 256 + n] * TSCALE;
    float v6 = W1[(kb + 18) * 256 + n] * TSCALE;
    float v7 = W1[(kb + 19) * 256 + n] * TSCALE;
    int4v d = {pk2(v0, v1), pk2(v2, v3), pk2(v4, v5), pk2(v6, v7)};
    *(int4v*)(ldsb + W1F_OFF + pi * 16) = d;
  }
  // ---- stage W2 frags: fid = p*8 + tb ----
  #pragma unroll 1
  for (int it = 0; it < 8; it++) {
    const int pi = it * 512 + tid;
    const int fid = pi >> 6, L = pi & 63;
    const int p = fid >> 3, tb = fid & 7;
    const int lf = L & 15, qf = L >> 4;
    const int d_out = tb * 16 + lf;        // output-dim (A-frag m-row)
    const int kb = p * 32 + qf * 4;        // logical hid base
    float v0 = W2[(kb + 0) * 128 + d_out];
    float v1 = W2[(kb + 1) * 128 + d_out];
    float v2 = W2[(kb + 2) * 128 + d_out];
    float v3 = W2[(kb + 3) * 128 + d_out];
    float v4 = W2[(kb + 16) * 128 + d_out];
    float v5 = W2[(kb + 17) * 128 + d_out];
    float v6 = W2[(kb + 18) * 128 + d_out];
    float v7 = W2[(kb + 19) * 128 + d_out];
    int4v d = {pk2(v0, v1), pk2(v2, v3), pk2(v4, v5), pk2(v6, v7)};
    *(int4v*)(ldsb + W2F_OFF + pi * 16) = d;
  }
  if (tid < 256) b1f[tid] = b1[tid] * TSCALE;
  if (tid < 50) dtf[tid] = ts[tid + 1] - ts[tid];

  // ---- b2 resident per-lane (C-layout columns) ----
  float4v b2v[8];
  #pragma unroll
  for (int tb = 0; tb < 8; tb++)
    b2v[tb] = *(const float4v*)&b2[tb * 16 + q * 4];

  // ---- load h: 16x16 C-layout. h4[tb][r] = h[row][tb*16 + q*4 + r] ----
  float4v h4[8];
  #pragma unroll
  for (int tb = 0; tb < 8; tb++)
    h4[tb] = *(const float4v*)&inp[row * 128 + tb * 16 + q * 4];

  __syncthreads();  // the only barrier

  // per-lane frag base pointers (reads: base + fid*64 int4vs + immediate)
  const int4v* w1f = (const int4v*)(ldsb + W1F_OFF) + lane;
  const int4v* w2f = (const int4v*)(ldsb + W2F_OFF) + lane;

  // ---- W2 chunks 3..6 (frags 24..55) into the idle AGPR half:
  // 32 frags x 4 regs = 128 AGPRs. Class bound by mfma_a "a" uses. ----
  short8 w2c[32];
  #pragma unroll
  for (int i = 0; i < 32; i++)
    w2c[i] = __builtin_bit_cast(short8, w2f[(24 + i) * 64]);

  #pragma unroll 1
  for (int s = 0; s < 50; s++) {
    const float dt = dtf[s];
    const float m2dt = -2.0f * dt;

    // ---- state -> 4 B-frags (pure register packing) ----
    FB hb[4];
    #pragma unroll
    for (int kc = 0; kc < 4; kc++)
      hb[kc].i = packfrag(h4[2 * kc], h4[2 * kc + 1]);

    // ---- rotated depth-1 pipeline over 8 hid-pair chunks ----
    // prologue: mm1(0) + act(0) -> af (trans latency exposed once/step)
    FB af;
    {
      FB wA[4], wB[4];
      #pragma unroll
      for (int c = 0; c < 4; c++) {
        wA[c].i = w1f[(0 * 4 + c) * 64];
        wB[c].i = w1f[(1 * 4 + c) * 64];
      }
      float4v g0 = *(const float4v*)&b1f[0 * 16 + q * 4];
      float4v g1 = *(const float4v*)&b1f[1 * 16 + q * 4];
      #pragma unroll
      for (int c = 0; c < 4; c++) {
        g0 = MFMA16(wA[c].s, hb[c].s, g0);
        g1 = MFMA16(wB[c].s, hb[c].s, g1);
      }
      float4v a0, a1;
      #pragma unroll
      for (int r = 0; r < 4; r++) {
        a0[r] = fmaf(__builtin_amdgcn_rcpf(__builtin_amdgcn_exp2f(g0[r]) + 1.0f), m2dt, dt);
        a1[r] = fmaf(__builtin_amdgcn_rcpf(__builtin_amdgcn_exp2f(g1[r]) + 1.0f), m2dt, dt);
      }
      af.i = packfrag(a0, a1);
    }

    // steady A: p=1..3, mm2(p-1) = chunks 0..2 streamed from LDS (builtin)
    #pragma unroll 1
    for (int p = 1; p <= 3; p++) {
      const int nt0 = 2 * p, nt1 = 2 * p + 1;
      FB wA[4], wB[4];
      #pragma unroll
      for (int c = 0; c < 4; c++) {
        wA[c].i = w1f[(nt0 * 4 + c) * 64];
        wB[c].i = w1f[(nt1 * 4 + c) * 64];
      }
      float4v g0 = *(const float4v*)&b1f[nt0 * 16 + q * 4];
      float4v g1 = *(const float4v*)&b1f[nt1 * 16 + q * 4];
      #pragma unroll
      for (int c = 0; c < 4; c++) {
        g0 = MFMA16(wA[c].s, hb[c].s, g0);
        g1 = MFMA16(wB[c].s, hb[c].s, g1);
      }
      {
        FB w2r[8];
        #pragma unroll
        for (int tb = 0; tb < 8; tb++)
          w2r[tb].i = w2f[((p - 1) * 8 + tb) * 64];
        #pragma unroll
        for (int tb = 0; tb < 8; tb++)
          h4[tb] = MFMA16(w2r[tb].s, af.s, h4[tb]);
      }
      float4v a0, a1;
      #pragma unroll
      for (int r = 0; r < 4; r++) {
        a0[r] = fmaf(__builtin_amdgcn_rcpf(__builtin_amdgcn_exp2f(g0[r]) + 1.0f), m2dt, dt);
        a1[r] = fmaf(__builtin_amdgcn_rcpf(__builtin_amdgcn_exp2f(g1[r]) + 1.0f), m2dt, dt);
      }
      af.i = packfrag(a0, a1);
    }

    // steady B: p=4..7 UNROLLED, mm2(p-1) = chunks 3..6 from AGPR (asm)
    #pragma unroll
    for (int p = 4; p <= 7; p++) {
      const int nt0 = 2 * p, nt1 = 2 * p + 1;
      FB wA[4], wB[4];
      #pragma unroll
      for (int c = 0; c < 4; c++) {
        wA[c].i = w1f[(nt0 * 4 + c) * 64];
        wB[c].i = w1f[(nt1 * 4 + c) * 64];
      }
      float4v g0 = *(const float4v*)&b1f[nt0 * 16 + q * 4];
      float4v g1 = *(const float4v*)&b1f[nt1 * 16 + q * 4];
      #pragma unroll
      for (int c = 0; c < 4; c++) {
        g0 = MFMA16(wA[c].s, hb[c].s, g0);
        g1 = MFMA16(wB[c].s, hb[c].s, g1);
      }
      // mm2(p-1) from the AGPR cache (static indices; asm-constrained uses)
      #pragma unroll
      for (int tb = 0; tb < 8; tb++)
        mfma_a(h4[tb], w2c[(p - 4) * 8 + tb], af.s);
      float4v a0, a1;
      #pragma unroll
      for (int r = 0; r < 4; r++) {
        a0[r] = fmaf(__builtin_amdgcn_rcpf(__builtin_amdgcn_exp2f(g0[r]) + 1.0f), m2dt, dt);
        a1[r] = fmaf(__builtin_amdgcn_rcpf(__builtin_amdgcn_exp2f(g1[r]) + 1.0f), m2dt, dt);
      }
      af.i = packfrag(a0, a1);
    }

    // epilogue: mm2(7) streamed from LDS (BUILTIN -> compiler emits the
    // hazard nops before the VALU b2-add / next-step packfrag reads of h4)
    {
      FB w2r[8];
      #pragma unroll
      for (int tb = 0; tb < 8; tb++)
        w2r[tb].i = w2f[(7 * 8 + tb) * 64];
      #pragma unroll
      for (int tb = 0; tb < 8; tb++)
        h4[tb] = MFMA16(w2r[tb].s, af.s, h4[tb]);
    }

    // ---- h += dt * b2 ----
    #pragma unroll
    for (int tb = 0; tb < 8; tb++)
      #pragma unroll
      for (int r = 0; r < 4; r++)
        h4[tb][r] = fmaf(dt, b2v[tb][r], h4[tb][r]);
  }

  // ---- store ----
  #pragma unroll
  for (int tb = 0; tb < 8; tb++)
    *(float4v*)&out[row * 128 + tb * 16 + q * 4] = h4[tb];
}

extern "C" void kernel_launch(void* const* d_in, const int* in_sizes, int n_in,
                              void* d_out, int out_size, void* d_ws, size_t ws_size,
                              hipStream_t stream) {
  const float* inp = (const float*)d_in[0];
  const float* ts  = (const float*)d_in[1];
  const float* W1  = (const float*)d_in[2];
  const float* b1  = (const float*)d_in[3];
  const float* W2  = (const float*)d_in[4];
  const float* b2  = (const float*)d_in[5];
  hipLaunchKernelGGL(ode_kernel, dim3(256), dim3(512), 0, stream,
                     inp, ts, W1, b1, W2, b2, (float*)d_out);
}